// Round 5
// baseline (255.964 us; speedup 1.0000x reference)
//
#include <hip/hip_runtime.h>
#include <hip/hip_bf16.h>
#include <float.h>

// Problem constants
constexpr int B  = 64;
constexpr int C  = 256;
constexpr int HW = 1024;   // 32*32
constexpr int K  = 1024;
constexpr float BETA = 0.25f;
constexpr float NTOT_INV = 1.0f / 16777216.0f;  // 1 / (64*256*32*32)

typedef __attribute__((ext_vector_type(8))) short bf16x8;
typedef __attribute__((ext_vector_type(4))) float floatx4;

union U16 { uint4 u; bf16x8 b; };

__device__ inline unsigned short f2bf(float x) {
    unsigned u = __float_as_uint(x);
    return (unsigned short)((u + 0x7FFFu + ((u >> 16) & 1u)) >> 16);  // RNE
}

// --- kernel 1: emb fp32 -> bf16 (row-major) + esq1[k] = 1 + ||e_k||^2 ---
// also zeroes loss accumulators + completion counter (block 0).
__global__ __launch_bounds__(256) void prep_kernel(const float* __restrict__ emb,
                                                   short* __restrict__ emb_bf,
                                                   float* __restrict__ esq1,
                                                   float* __restrict__ acc_loss) {
    if (blockIdx.x == 0 && threadIdx.x < 4) acc_loss[threadIdx.x] = 0.0f;
    const int wid  = threadIdx.x >> 6;
    const int lane = threadIdx.x & 63;
    const int k    = blockIdx.x * 4 + wid;
    const float4 v = *(const float4*)(emb + (size_t)k * C + lane * 4);
    ushort4 pk = { f2bf(v.x), f2bf(v.y), f2bf(v.z), f2bf(v.w) };
    *(ushort4*)(emb_bf + (size_t)k * C + lane * 4) = pk;
    float s = v.x * v.x + v.y * v.y + v.z * v.z + v.w * v.w;
#pragma unroll
    for (int off = 32; off > 0; off >>= 1) s += __shfl_down(s, off, 64);
    if (lane == 0) esq1[k] = 1.0f + s;
}

// --- kernel 2: distances + argmin. 2048 single-wave blocks. ---
// block b = (tile = b>>1, khalf = b&1): 64 tokens x 512 codes.
// Publishes packed (dist|code) via global atomicMin (monotone for d>0).
__global__ __launch_bounds__(64) void vq_dist(const float* __restrict__ z,
                                              const short* __restrict__ emb_bf,
                                              const float* __restrict__ esq1,
                                              unsigned int* __restrict__ bestTok) {
    // transpose buffer: [32 ch-blocks][64 tok][8 ch] bf16 = 32 KB
    __shared__ short Zs[32 * 512];

    const int L   = threadIdx.x;   // lane 0..63
    const int q   = L >> 4;        // quad
    const int l15 = L & 15;

    const int tile = blockIdx.x >> 1;          // 0..1023
    const int kh   = (blockIdx.x & 1) * 512;   // K half base
    const int b    = tile >> 4;                // batch
    const int hw0  = (tile & 15) * 64;         // position tile base
    const float* zb = z + (size_t)b * C * HW + hw0;

    // ---- phase 1: transpose 64 tokens x 256 ch into LDS (coalesced reads) ----
#pragma unroll 4
    for (int c = 0; c < C; c += 4) {
        float v0 = zb[(size_t)(c + 0) * HW + L];
        float v1 = zb[(size_t)(c + 1) * HW + L];
        float v2 = zb[(size_t)(c + 2) * HW + L];
        float v3 = zb[(size_t)(c + 3) * HW + L];
        ushort4 pk = { f2bf(v0), f2bf(v1), f2bf(v2), f2bf(v3) };
        *(ushort4*)&Zs[(c >> 3) * 512 + L * 8 + (c & 7)] = pk;
    }
    __syncthreads();

    // ---- phase 2: B-fragments into registers (held for whole K loop) ----
    // zfrag[t][ks]: token = t*16 + l15, ch = ks*32 + q*8 + j
    bf16x8 zfrag[4][8];
#pragma unroll
    for (int t = 0; t < 4; ++t)
#pragma unroll
        for (int ks = 0; ks < 8; ++ks)
            zfrag[t][ks] = *(const bf16x8*)&Zs[(ks * 4 + q) * 512 + (t * 16 + l15) * 8];

    // ---- phase 3: 8 chunks of 64 codes, no barriers, A-frags direct from L2 ----
    unsigned int best[4] = {0xFFFFFFFFu, 0xFFFFFFFFu, 0xFFFFFFFFu, 0xFFFFFFFFu};

    for (int ch = 0; ch < 8; ++ch) {
        const int k0 = kh + ch * 64;
        floatx4 acc[4][4];   // [m code tile][t token tile]
#pragma unroll
        for (int m = 0; m < 4; ++m)
#pragma unroll
            for (int t = 0; t < 4; ++t) acc[m][t] = (floatx4){0.f, 0.f, 0.f, 0.f};

#pragma unroll
        for (int ks = 0; ks < 8; ++ks) {
            U16 a[4];
#pragma unroll
            for (int m = 0; m < 4; ++m)
                a[m].u = *(const uint4*)(emb_bf + ((size_t)(k0 + m * 16 + l15) << 8) + ks * 32 + q * 8);
#pragma unroll
            for (int m = 0; m < 4; ++m)
#pragma unroll
                for (int t = 0; t < 4; ++t)
                    acc[m][t] = __builtin_amdgcn_mfma_f32_16x16x32_bf16(a[m].b, zfrag[t][ks], acc[m][t], 0, 0, 0);
        }

        // distances + packed argmin (d positive: float bits monotone; low 10 bits = code)
#pragma unroll
        for (int m = 0; m < 4; ++m) {
            const float4 eq = *(const float4*)&esq1[k0 + m * 16 + q * 4];
            const float eqa[4] = {eq.x, eq.y, eq.z, eq.w};
#pragma unroll
            for (int r = 0; r < 4; ++r) {
                const unsigned int code = (unsigned int)(k0 + m * 16 + q * 4 + r);
#pragma unroll
                for (int t = 0; t < 4; ++t) {
                    float d = fmaf(-2.0f, acc[m][t][r], eqa[r]);
                    unsigned int u = (__float_as_uint(d) & 0xFFFFFC00u) | code;
                    best[t] = best[t] < u ? best[t] : u;
                }
            }
        }
    }

    // ---- phase 4: butterfly across quads, then device-scope atomicMin ----
#pragma unroll
    for (int t = 0; t < 4; ++t) {
        unsigned int o = (unsigned int)__shfl_xor((int)best[t], 16, 64);
        best[t] = best[t] < o ? best[t] : o;
        o = (unsigned int)__shfl_xor((int)best[t], 32, 64);
        best[t] = best[t] < o ? best[t] : o;
    }
    if (q == 0) {
#pragma unroll
        for (int t = 0; t < 4; ++t)
            atomicMin(&bestTok[b * HW + hw0 + t * 16 + l15], best[t]);
    }
}

// --- kernel 3: streaming epilogue + loss. 1024 blocks x 256 thr. ---
// Wave w of a block handles channel quarter [w*64, w*64+64) for 64 tokens.
__global__ __launch_bounds__(256) void vq_out(const float* __restrict__ z,
                                              const float* __restrict__ emb,
                                              const unsigned int* __restrict__ bestTok,
                                              float* __restrict__ out,
                                              float* __restrict__ acc_loss,
                                              float* __restrict__ out_loss) {
    __shared__ float wred[8];

    const int tid = threadIdx.x;
    const int w   = tid >> 6;      // wave -> channel quarter
    const int L   = tid & 63;      // lane -> token
    const int b   = blockIdx.x >> 4;
    const int hw0 = (blockIdx.x & 15) * 64;

    const int km = (int)(bestTok[b * HW + hw0 + L] & 1023u);
    const float* erow = emb + (size_t)km * C;

    float s_sq = 0.0f, s_d = 0.0f;
    const size_t base = (size_t)b * C * HW + hw0 + L;
    const int c0 = w * 64;
#pragma unroll 4
    for (int c = c0; c < c0 + 64; c += 4) {
        float4 ev = *(const float4*)&erow[c];
        const float eva[4] = {ev.x, ev.y, ev.z, ev.w};
#pragma unroll
        for (int j = 0; j < 4; ++j) {
            float zv = z[base + (size_t)(c + j) * HW];
            float diff = eva[j] - zv;                      // z_q - z
            out[base + (size_t)(c + j) * HW] = zv + diff;  // straight-through fwd
            s_sq = fmaf(diff, diff, s_sq);
            s_d += diff;
        }
    }
#pragma unroll
    for (int off = 32; off > 0; off >>= 1) {
        s_sq += __shfl_down(s_sq, off, 64);
        s_d  += __shfl_down(s_d,  off, 64);
    }
    if (L == 0) { wred[w] = s_sq; wred[4 + w] = s_d; }
    __syncthreads();

    // block partials -> global; last block finalizes the loss
    if (tid == 0) {
        float a = wred[0] + wred[1] + wred[2] + wred[3];
        float d = wred[4] + wred[5] + wred[6] + wred[7];
        atomicAdd(&acc_loss[0], a);
        atomicAdd(&acc_loss[1], d);
        __threadfence();
        unsigned int old = atomicAdd((unsigned int*)&acc_loss[2], 1u);
        if (old == 1023u) {
            float sa = atomicAdd(&acc_loss[0], 0.0f);   // coherent read
            float sd = atomicAdd(&acc_loss[1], 0.0f);
            out_loss[0] = sa * NTOT_INV + BETA * (sd * NTOT_INV);
        }
    }
}

extern "C" void kernel_launch(void* const* d_in, const int* in_sizes, int n_in,
                              void* d_out, int out_size, void* d_ws, size_t ws_size,
                              hipStream_t stream) {
    const float* z   = (const float*)d_in[0];   // [64,256,32,32]
    const float* emb = (const float*)d_in[1];   // [1024,256]
    float* out = (float*)d_out;                 // [16777216 z_q] + [1 loss]
    float* ws  = (float*)d_ws;

    // workspace layout
    float* acc  = ws;                               // [0]=sum_sq [1]=sum_d [2]=counter
    float* esq1 = ws + 64;                          // 1024 floats
    short* emb_bf = (short*)(ws + 64 + 1024);       // 1024*256 bf16 = 512 KB
    unsigned int* bestTok = (unsigned int*)((char*)emb_bf + (size_t)K * C * sizeof(short));  // 64K u32

    hipMemsetAsync(bestTok, 0xFF, (size_t)B * HW * sizeof(unsigned int), stream);
    prep_kernel<<<dim3(K / 4), 256, 0, stream>>>(emb, emb_bf, esq1, acc);
    vq_dist<<<dim3(2048), 64, 0, stream>>>(z, emb_bf, esq1, bestTok);
    vq_out<<<dim3(1024), 256, 0, stream>>>(z, emb, bestTok, out, acc,
                                           out + (size_t)B * C * HW);
}

// Round 6
// 228.477 us; speedup vs baseline: 1.1203x; 1.1203x over previous
//
#include <hip/hip_runtime.h>
#include <hip/hip_bf16.h>
#include <float.h>

// Problem constants
constexpr int B  = 64;
constexpr int C  = 256;
constexpr int HW = 1024;   // 32*32
constexpr int K  = 1024;
constexpr float BETA = 0.25f;
constexpr float NTOT_INV = 1.0f / 16777216.0f;  // 1 / (64*256*32*32)

typedef __attribute__((ext_vector_type(8))) short bf16x8;
typedef __attribute__((ext_vector_type(4))) float floatx4;

union U16 { uint4 u; bf16x8 b; };

__device__ inline unsigned short f2bf(float x) {
    unsigned u = __float_as_uint(x);
    return (unsigned short)((u + 0x7FFFu + ((u >> 16) & 1u)) >> 16);  // RNE
}

// --- kernel 1: emb fp32 -> bf16 in MFMA A-operand order + esq1 + inits ---
// embA unit u = ((cc*8 + ks)*4 + m)*64 + q*16 + l15  (16 B units), where
// code = cc*64 + m*16 + l15, channels = ks*32 + q*8 + j (j=0..7).
// Also: bestTok init (65536 threads, 1:1) and loss accumulator zeroing.
__global__ __launch_bounds__(256) void prep_kernel(const float* __restrict__ emb,
                                                   short* __restrict__ embA,
                                                   float* __restrict__ esq1,
                                                   float* __restrict__ acc_loss,
                                                   unsigned int* __restrict__ bestTok) {
    if (blockIdx.x == 0 && threadIdx.x < 4) acc_loss[threadIdx.x] = 0.0f;
    bestTok[blockIdx.x * 256 + threadIdx.x] = 0xFFFFFFFFu;

    const int wid  = threadIdx.x >> 6;
    const int lane = threadIdx.x & 63;
    const int k    = blockIdx.x * 4 + wid;   // code
    const int c0   = lane * 4;               // first of 4 channels
    const float4 v = *(const float4*)(emb + (size_t)k * C + c0);
    ushort4 pk = { f2bf(v.x), f2bf(v.y), f2bf(v.z), f2bf(v.w) };

    const int cc = k >> 6, m = (k >> 4) & 3, l15 = k & 15;
    const int ks = c0 >> 5, q = (c0 >> 3) & 3, j = c0 & 7;   // j in {0,4}
    const size_t u16 = (size_t)(((cc * 8 + ks) * 4 + m) * 64 + q * 16 + l15);
    *(ushort4*)(embA + u16 * 8 + j) = pk;

    float s = v.x * v.x + v.y * v.y + v.z * v.z + v.w * v.w;
#pragma unroll
    for (int off = 32; off > 0; off >>= 1) s += __shfl_down(s, off, 64);
    if (lane == 0) esq1[k] = 1.0f + s;
}

// --- kernel 2: distances + argmin. 2048 single-wave blocks, ZERO LDS. ---
// block = (tile = bid>>1, khalf = bid&1): 64 tokens x 512 codes.
// Z fragments built by direct strided loads; A-frags one coalesced 1KB load each.
// Publishes packed (dist|code) via global atomicMin (monotone: d > 0).
__global__ __launch_bounds__(64) void vq_dist(const float* __restrict__ z,
                                              const uint4* __restrict__ embA4,
                                              const float* __restrict__ esq1,
                                              unsigned int* __restrict__ bestTok) {
    const int L   = threadIdx.x;   // lane 0..63
    const int q   = L >> 4;        // quad
    const int l15 = L & 15;

    const int tile = blockIdx.x >> 1;          // 0..1023
    const int kh8  = (blockIdx.x & 1) * 8;     // chunk base (64-code chunks)
    const int b    = tile >> 4;                // batch
    const int hw0  = (tile & 15) * 64;         // position tile base
    const float* zb = z + (size_t)b * C * HW + hw0 + l15;

    // ---- phase 1: build B-fragments directly from global (no LDS, no barrier) ----
    // zfrag[t][ks]: token = t*16 + l15, ch = ks*32 + q*8 + j
    bf16x8 zfrag[4][8];
#pragma unroll
    for (int t = 0; t < 4; ++t) {
#pragma unroll
        for (int ks = 0; ks < 8; ++ks) {
            const float* p = zb + t * 16 + (size_t)(ks * 32 + q * 8) * HW;
            float v[8];
#pragma unroll
            for (int j = 0; j < 8; ++j) v[j] = p[(size_t)j * HW];
            union { unsigned short s[8]; bf16x8 bv; } pk;
#pragma unroll
            for (int j = 0; j < 8; ++j) pk.s[j] = f2bf(v[j]);
            zfrag[t][ks] = pk.bv;
        }
    }

    // ---- phase 2: 8 chunks of 64 codes; A-frags coalesced from L2 ----
    unsigned int best[4] = {0xFFFFFFFFu, 0xFFFFFFFFu, 0xFFFFFFFFu, 0xFFFFFFFFu};

    for (int ch = 0; ch < 8; ++ch) {
        const int cc = kh8 + ch;          // 64-code chunk index
        floatx4 acc[4][4];                // [m code tile][t token tile]
#pragma unroll
        for (int m = 0; m < 4; ++m)
#pragma unroll
            for (int t = 0; t < 4; ++t) acc[m][t] = (floatx4){0.f, 0.f, 0.f, 0.f};

#pragma unroll
        for (int ks = 0; ks < 8; ++ks) {
            U16 a[4];
#pragma unroll
            for (int m = 0; m < 4; ++m)
                a[m].u = embA4[(size_t)(((cc * 8 + ks) * 4 + m) * 64 + L)];
#pragma unroll
            for (int m = 0; m < 4; ++m)
#pragma unroll
                for (int t = 0; t < 4; ++t)
                    acc[m][t] = __builtin_amdgcn_mfma_f32_16x16x32_bf16(a[m].b, zfrag[t][ks], acc[m][t], 0, 0, 0);
        }

        // distances + packed argmin (d positive: float bits monotone; low 10 bits = code)
#pragma unroll
        for (int m = 0; m < 4; ++m) {
            const float4 eq = *(const float4*)&esq1[cc * 64 + m * 16 + q * 4];
            const float eqa[4] = {eq.x, eq.y, eq.z, eq.w};
#pragma unroll
            for (int r = 0; r < 4; ++r) {
                const unsigned int code = (unsigned int)(cc * 64 + m * 16 + q * 4 + r);
#pragma unroll
                for (int t = 0; t < 4; ++t) {
                    float d = fmaf(-2.0f, acc[m][t][r], eqa[r]);
                    unsigned int u = (__float_as_uint(d) & 0xFFFFFC00u) | code;
                    best[t] = best[t] < u ? best[t] : u;
                }
            }
        }
    }

    // ---- phase 3: butterfly across quads, then device-scope atomicMin ----
#pragma unroll
    for (int t = 0; t < 4; ++t) {
        unsigned int o = (unsigned int)__shfl_xor((int)best[t], 16, 64);
        best[t] = best[t] < o ? best[t] : o;
        o = (unsigned int)__shfl_xor((int)best[t], 32, 64);
        best[t] = best[t] < o ? best[t] : o;
    }
    if (q == 0) {
#pragma unroll
        for (int t = 0; t < 4; ++t)
            atomicMin(&bestTok[b * HW + hw0 + t * 16 + l15], best[t]);
    }
}

// --- kernel 3: streaming epilogue + loss. 1024 blocks x 256 thr. ---
// Wave w handles channel quarter [w*64, w*64+64) for the block's 64 tokens.
__global__ __launch_bounds__(256) void vq_out(const float* __restrict__ z,
                                              const float* __restrict__ emb,
                                              const unsigned int* __restrict__ bestTok,
                                              float* __restrict__ out,
                                              float* __restrict__ acc_loss,
                                              float* __restrict__ out_loss) {
    __shared__ float wred[8];

    const int tid = threadIdx.x;
    const int w   = tid >> 6;      // wave -> channel quarter
    const int L   = tid & 63;      // lane -> token
    const int b   = blockIdx.x >> 4;
    const int hw0 = (blockIdx.x & 15) * 64;

    const int km = (int)(bestTok[b * HW + hw0 + L] & 1023u);
    const float* erow = emb + (size_t)km * C;

    float s_sq = 0.0f, s_d = 0.0f;
    const size_t base = (size_t)b * C * HW + hw0 + L;
    const int c0 = w * 64;
#pragma unroll 4
    for (int c = c0; c < c0 + 64; c += 4) {
        float4 ev = *(const float4*)&erow[c];
        const float eva[4] = {ev.x, ev.y, ev.z, ev.w};
#pragma unroll
        for (int j = 0; j < 4; ++j) {
            float zv = z[base + (size_t)(c + j) * HW];
            float diff = eva[j] - zv;                      // z_q - z
            out[base + (size_t)(c + j) * HW] = zv + diff;  // straight-through fwd
            s_sq = fmaf(diff, diff, s_sq);
            s_d += diff;
        }
    }
#pragma unroll
    for (int off = 32; off > 0; off >>= 1) {
        s_sq += __shfl_down(s_sq, off, 64);
        s_d  += __shfl_down(s_d,  off, 64);
    }
    if (L == 0) { wred[w] = s_sq; wred[4 + w] = s_d; }
    __syncthreads();

    // block partials -> global; last block finalizes the loss
    if (tid == 0) {
        float a = wred[0] + wred[1] + wred[2] + wred[3];
        float d = wred[4] + wred[5] + wred[6] + wred[7];
        atomicAdd(&acc_loss[0], a);
        atomicAdd(&acc_loss[1], d);
        __threadfence();
        unsigned int old = atomicAdd((unsigned int*)&acc_loss[2], 1u);
        if (old == 1023u) {
            float sa = atomicAdd(&acc_loss[0], 0.0f);   // coherent read
            float sd = atomicAdd(&acc_loss[1], 0.0f);
            out_loss[0] = sa * NTOT_INV + BETA * (sd * NTOT_INV);
        }
    }
}

extern "C" void kernel_launch(void* const* d_in, const int* in_sizes, int n_in,
                              void* d_out, int out_size, void* d_ws, size_t ws_size,
                              hipStream_t stream) {
    const float* z   = (const float*)d_in[0];   // [64,256,32,32]
    const float* emb = (const float*)d_in[1];   // [1024,256]
    float* out = (float*)d_out;                 // [16777216 z_q] + [1 loss]
    float* ws  = (float*)d_ws;

    // workspace layout
    float* acc  = ws;                               // [0]=sum_sq [1]=sum_d [2]=counter
    float* esq1 = ws + 64;                          // 1024 floats
    short* embA = (short*)(ws + 64 + 1024);         // 512 KB, MFMA A-operand order
    unsigned int* bestTok = (unsigned int*)((char*)embA + (size_t)K * C * sizeof(short));  // 64K u32

    prep_kernel<<<dim3(256), 256, 0, stream>>>(emb, embA, esq1, acc, bestTok);
    vq_dist<<<dim3(2048), 64, 0, stream>>>(z, (const uint4*)embA, esq1, bestTok);
    vq_out<<<dim3(1024), 256, 0, stream>>>(z, emb, bestTok, out, acc,
                                           out + (size_t)B * C * HW);
}